// Round 3
// baseline (76.940 us; speedup 1.0000x reference)
//
#include <hip/hip_runtime.h>
#include <hip/hip_fp16.h>

typedef float f32x4 __attribute__((ext_vector_type(4)));

#define N_SAMPLES 64
#define M_ELEMS   307200            // 480*640 per-sample elements
#define M4        76800             // float4 per sample
#define BLOCK     256
#define BPS       30                // blocks per sample
#define TPS       (BPS * BLOCK)     // 7680 threads per sample
#define ITERS1    (M4 / TPS)        // 10 float4 per thread, exact
#define Q16       38400             // uint4 (8 halves) per sample in ws
#define ITERS2    (Q16 / TPS)       // 5, exact

__device__ __forceinline__ float wave_reduce_max(float v) {
    #pragma unroll
    for (int off = 32; off > 0; off >>= 1)
        v = fmaxf(v, __shfl_down(v, off, 64));
    return v;
}
__device__ __forceinline__ float wave_reduce_sum(float v) {
    #pragma unroll
    for (int off = 32; off > 0; off >>= 1)
        v += __shfl_down(v, off, 64);
    return v;
}

// K1: nt-stream inputs from HBM (no L3 allocation), per-sample max of |d|,
//     compress |d| to fp16 into ws (cached stores -> L3-resident for K2).
__global__ __launch_bounds__(BLOCK) void berhu_k1(
        const float* __restrict__ pred,
        const float* __restrict__ targ,
        unsigned int* __restrict__ maxbits,
        __half* __restrict__ adbuf) {
    const int n = blockIdx.y;
    const f32x4* p = (const f32x4*)(pred + (size_t)n * M_ELEMS);
    const f32x4* t = (const f32x4*)(targ + (size_t)n * M_ELEMS);
    uint2* w = (uint2*)(adbuf + (size_t)n * M_ELEMS);   // 8B = 4 halves per float4

    float m = 0.0f;
    int i = blockIdx.x * BLOCK + threadIdx.x;
    #pragma unroll
    for (int k = 0; k < ITERS1; ++k, i += TPS) {
        f32x4 a = __builtin_nontemporal_load(p + i);
        f32x4 b = __builtin_nontemporal_load(t + i);
        float ad0 = fabsf(a[0] - b[0]);
        float ad1 = fabsf(a[1] - b[1]);
        float ad2 = fabsf(a[2] - b[2]);
        float ad3 = fabsf(a[3] - b[3]);
        m = fmaxf(m, fmaxf(fmaxf(ad0, ad1), fmaxf(ad2, ad3)));
        __half2 h0 = __floats2half2_rn(ad0, ad1);
        __half2 h1 = __floats2half2_rn(ad2, ad3);
        uint2 u;
        u.x = __builtin_bit_cast(unsigned int, h0);
        u.y = __builtin_bit_cast(unsigned int, h1);
        w[i] = u;
    }

    m = wave_reduce_max(m);
    __shared__ float smax[BLOCK / 64];
    const int wid  = threadIdx.x >> 6;
    const int lane = threadIdx.x & 63;
    if (lane == 0) smax[wid] = m;
    __syncthreads();
    if (threadIdx.x == 0) {
        float bm = smax[0];
        #pragma unroll
        for (int wq = 1; wq < BLOCK / 64; ++wq) bm = fmaxf(bm, smax[wq]);
        atomicMax(&maxbits[n], __float_as_uint(bm));   // |d|>=0: bit compare == float compare
    }
}

// K2: read fp16 |d| from L3-resident ws, BerHu sum -> scaled atomicAdd into out[0]
__global__ __launch_bounds__(BLOCK) void berhu_k2(
        const __half* __restrict__ adbuf,
        const unsigned int* __restrict__ maxbits,
        float* __restrict__ out) {
    const int n = blockIdx.y;
    const float c = __uint_as_float(maxbits[n]) * 0.2f;   // max/5
    const float c2 = c * c;
    const float inv2c = (c > 0.0f) ? (0.5f / c) : 0.0f;

    const uint4* r = (const uint4*)(adbuf + (size_t)n * M_ELEMS);
    float s = 0.0f;
    int i = blockIdx.x * BLOCK + threadIdx.x;
    #pragma unroll
    for (int k = 0; k < ITERS2; ++k, i += TPS) {
        uint4 u = r[i];
        #pragma unroll
        for (int q = 0; q < 4; ++q) {
            unsigned int uw = (q == 0) ? u.x : (q == 1) ? u.y : (q == 2) ? u.z : u.w;
            __half2 h = __builtin_bit_cast(__half2, uw);
            float2 f = __half22float2(h);
            s += (f.x <= c) ? f.x : (f.x * f.x + c2) * inv2c;
            s += (f.y <= c) ? f.y : (f.y * f.y + c2) * inv2c;
        }
    }

    s = wave_reduce_sum(s);
    __shared__ float ssum[BLOCK / 64];
    const int wid  = threadIdx.x >> 6;
    const int lane = threadIdx.x & 63;
    if (lane == 0) ssum[wid] = s;
    __syncthreads();
    if (threadIdx.x == 0) {
        float bs = ssum[0];
        #pragma unroll
        for (int wq = 1; wq < BLOCK / 64; ++wq) bs += ssum[wq];
        atomicAdd(out, bs * (1.0f / ((float)M_ELEMS * (float)N_SAMPLES)));
    }
}

// ---- fallback (ws too small): plain two-pass over inputs ----
__global__ __launch_bounds__(BLOCK) void fb_max(
        const float* __restrict__ pred, const float* __restrict__ targ,
        unsigned int* __restrict__ maxbits) {
    const int n = blockIdx.y;
    const f32x4* p = (const f32x4*)(pred + (size_t)n * M_ELEMS);
    const f32x4* t = (const f32x4*)(targ + (size_t)n * M_ELEMS);
    float m = 0.0f;
    for (int i = blockIdx.x * BLOCK + threadIdx.x; i < M4; i += TPS) {
        f32x4 a = p[i], b = t[i];
        m = fmaxf(m, fmaxf(fmaxf(fabsf(a[0]-b[0]), fabsf(a[1]-b[1])),
                           fmaxf(fabsf(a[2]-b[2]), fabsf(a[3]-b[3]))));
    }
    m = wave_reduce_max(m);
    __shared__ float smax[BLOCK / 64];
    if ((threadIdx.x & 63) == 0) smax[threadIdx.x >> 6] = m;
    __syncthreads();
    if (threadIdx.x == 0) {
        float bm = smax[0];
        for (int wq = 1; wq < BLOCK / 64; ++wq) bm = fmaxf(bm, smax[wq]);
        atomicMax(&maxbits[n], __float_as_uint(bm));
    }
}
__global__ __launch_bounds__(BLOCK) void fb_sum(
        const float* __restrict__ pred, const float* __restrict__ targ,
        const unsigned int* __restrict__ maxbits, float* __restrict__ out) {
    const int n = blockIdx.y;
    const float c = __uint_as_float(maxbits[n]) * 0.2f;
    const float c2 = c * c;
    const float inv2c = (c > 0.0f) ? (0.5f / c) : 0.0f;
    const f32x4* p = (const f32x4*)(pred + (size_t)n * M_ELEMS);
    const f32x4* t = (const f32x4*)(targ + (size_t)n * M_ELEMS);
    float s = 0.0f;
    for (int i = blockIdx.x * BLOCK + threadIdx.x; i < M4; i += TPS) {
        f32x4 a = p[i], b = t[i];
        #pragma unroll
        for (int q = 0; q < 4; ++q) {
            float d = a[q] - b[q], ad = fabsf(d);
            s += (ad <= c) ? ad : (d * d + c2) * inv2c;
        }
    }
    s = wave_reduce_sum(s);
    __shared__ float ssum[BLOCK / 64];
    if ((threadIdx.x & 63) == 0) ssum[threadIdx.x >> 6] = s;
    __syncthreads();
    if (threadIdx.x == 0) {
        float bs = ssum[0];
        for (int wq = 1; wq < BLOCK / 64; ++wq) bs += ssum[wq];
        atomicAdd(out, bs * (1.0f / ((float)M_ELEMS * (float)N_SAMPLES)));
    }
}

extern "C" void kernel_launch(void* const* d_in, const int* in_sizes, int n_in,
                              void* d_out, int out_size, void* d_ws, size_t ws_size,
                              hipStream_t stream) {
    const float* pred = (const float*)d_in[0];
    const float* targ = (const float*)d_in[1];
    float* out = (float*)d_out;

    unsigned int* maxbits = (unsigned int*)d_ws;
    __half* adbuf = (__half*)((char*)d_ws + 256);
    const size_t need = 256 + (size_t)N_SAMPLES * M_ELEMS * sizeof(__half);

    // ws/out poisoned 0xAA, not re-poisoned between replays — zero every call.
    hipMemsetAsync(d_ws, 0, N_SAMPLES * sizeof(unsigned int), stream);
    hipMemsetAsync(d_out, 0, sizeof(float), stream);

    dim3 grid(BPS, N_SAMPLES);
    if (ws_size >= need) {
        berhu_k1<<<grid, BLOCK, 0, stream>>>(pred, targ, maxbits, adbuf);
        berhu_k2<<<grid, BLOCK, 0, stream>>>(adbuf, maxbits, out);
    } else {
        fb_max<<<grid, BLOCK, 0, stream>>>(pred, targ, maxbits);
        fb_sum<<<grid, BLOCK, 0, stream>>>(pred, targ, maxbits, out);
    }
}

// Round 4
// 71.078 us; speedup vs baseline: 1.0825x; 1.0825x over previous
//
#include <hip/hip_runtime.h>
#include <hip/hip_fp16.h>

typedef float f32x4 __attribute__((ext_vector_type(4)));

#define N_SAMPLES 64
#define M_ELEMS   307200              // 480*640 per-sample elements
#define M4        76800               // float4 per sample
#define BLOCK     256
#define BPS       20                  // blocks per sample
#define TPS       (BPS * BLOCK)       // 5120 threads per sample
#define ITERS     (M4 / TPS)          // 15 float4 per thread, exact
#define NBLOCKS   (BPS * N_SAMPLES)   // 1280 = exactly 5 blocks/CU on 256 CUs
#define NUM_CU    256
#define SCALE     (1.0f / ((float)M_ELEMS * (float)N_SAMPLES))

__device__ __forceinline__ float wave_reduce_max(float v) {
    #pragma unroll
    for (int off = 32; off > 0; off >>= 1)
        v = fmaxf(v, __shfl_down(v, off, 64));
    return v;
}
__device__ __forceinline__ float wave_reduce_sum(float v) {
    #pragma unroll
    for (int off = 32; off > 0; off >>= 1)
        v += __shfl_down(v, off, 64);
    return v;
}

// Fused single-read kernel: phase 1 streams inputs once, holds |d| as packed
// fp16 in 30 statically-indexed VGPRs; per-sample device-scope sync; phase 2
// computes BerHu from registers. Requires all NBLOCKS co-resident (gated on
// host by the occupancy query; 5 blocks/CU at <=102 VGPR via launch_bounds).
__global__ __launch_bounds__(BLOCK, 5) void berhu_fused(
        const float* __restrict__ pred,
        const float* __restrict__ targ,
        unsigned int* __restrict__ maxbits,
        unsigned int* __restrict__ done,
        float* __restrict__ out) {
    const int n = blockIdx.y;
    const f32x4* p = (const f32x4*)(pred + (size_t)n * M_ELEMS);
    const f32x4* t = (const f32x4*)(targ + (size_t)n * M_ELEMS);
    const int i0 = blockIdx.x * BLOCK + threadIdx.x;

    unsigned int adp[2 * ITERS];     // 30 VGPRs of packed half2 |d|
    float m = 0.0f;
    #pragma unroll
    for (int k = 0; k < ITERS; ++k) {
        f32x4 a = p[i0 + k * TPS];
        f32x4 b = t[i0 + k * TPS];
        float ad0 = fabsf(a[0] - b[0]);
        float ad1 = fabsf(a[1] - b[1]);
        float ad2 = fabsf(a[2] - b[2]);
        float ad3 = fabsf(a[3] - b[3]);
        m = fmaxf(m, fmaxf(fmaxf(ad0, ad1), fmaxf(ad2, ad3)));
        adp[2 * k]     = __builtin_bit_cast(unsigned int, __floats2half2_rn(ad0, ad1));
        adp[2 * k + 1] = __builtin_bit_cast(unsigned int, __floats2half2_rn(ad2, ad3));
    }

    // block-reduce max
    m = wave_reduce_max(m);
    __shared__ float sred[BLOCK / 64];
    __shared__ float sc;
    const int wid  = threadIdx.x >> 6;
    const int lane = threadIdx.x & 63;
    if (lane == 0) sred[wid] = m;
    __syncthreads();
    if (threadIdx.x == 0) {
        float bm = sred[0];
        #pragma unroll
        for (int w = 1; w < BLOCK / 64; ++w) bm = fmaxf(bm, sred[w]);
        atomicMax(&maxbits[n], __float_as_uint(bm));   // |d|>=0: bit cmp == float cmp
        __threadfence();                               // maxbits visible before done++
        atomicAdd(&done[n], 1u);
        // All NBLOCKS co-resident (host-gated) -> every block reaches here -> no deadlock.
        while (atomicMax(&done[n], 0u) < (unsigned)BPS)
            __builtin_amdgcn_s_sleep(2);
        // coherent read of the final max via idempotent atomic RMW
        sc = __uint_as_float(atomicMax(&maxbits[n], 0u)) * 0.2f;
    }
    __syncthreads();

    const float c = sc;
    const float c2 = c * c;
    const float inv2c = (c > 0.0f) ? (0.5f / c) : 0.0f;

    float s = 0.0f;
    #pragma unroll
    for (int k = 0; k < 2 * ITERS; ++k) {
        __half2 h = __builtin_bit_cast(__half2, adp[k]);
        float fx = __low2float(h);
        float fy = __high2float(h);
        s += (fx <= c) ? fx : (fx * fx + c2) * inv2c;
        s += (fy <= c) ? fy : (fy * fy + c2) * inv2c;
    }

    s = wave_reduce_sum(s);
    __syncthreads();                 // sred reuse
    if (lane == 0) sred[wid] = s;
    __syncthreads();
    if (threadIdx.x == 0) {
        float bs = sred[0];
        #pragma unroll
        for (int w = 1; w < BLOCK / 64; ++w) bs += sred[w];
        atomicAdd(out, bs * SCALE);
    }
}

// ---- fallback: proven two-pass (R1 structure) ----
__global__ __launch_bounds__(BLOCK) void fb_max(
        const float* __restrict__ pred, const float* __restrict__ targ,
        unsigned int* __restrict__ maxbits) {
    const int n = blockIdx.y;
    const f32x4* p = (const f32x4*)(pred + (size_t)n * M_ELEMS);
    const f32x4* t = (const f32x4*)(targ + (size_t)n * M_ELEMS);
    float m = 0.0f;
    for (int i = blockIdx.x * BLOCK + threadIdx.x; i < M4; i += TPS) {
        f32x4 a = p[i], b = t[i];
        m = fmaxf(m, fmaxf(fmaxf(fabsf(a[0]-b[0]), fabsf(a[1]-b[1])),
                           fmaxf(fabsf(a[2]-b[2]), fabsf(a[3]-b[3]))));
    }
    m = wave_reduce_max(m);
    __shared__ float smax[BLOCK / 64];
    if ((threadIdx.x & 63) == 0) smax[threadIdx.x >> 6] = m;
    __syncthreads();
    if (threadIdx.x == 0) {
        float bm = smax[0];
        for (int w = 1; w < BLOCK / 64; ++w) bm = fmaxf(bm, smax[w]);
        atomicMax(&maxbits[n], __float_as_uint(bm));
    }
}
__global__ __launch_bounds__(BLOCK) void fb_sum(
        const float* __restrict__ pred, const float* __restrict__ targ,
        const unsigned int* __restrict__ maxbits, float* __restrict__ out) {
    const int n = blockIdx.y;
    const float c = __uint_as_float(maxbits[n]) * 0.2f;
    const float c2 = c * c;
    const float inv2c = (c > 0.0f) ? (0.5f / c) : 0.0f;
    const f32x4* p = (const f32x4*)(pred + (size_t)n * M_ELEMS);
    const f32x4* t = (const f32x4*)(targ + (size_t)n * M_ELEMS);
    float s = 0.0f;
    for (int i = blockIdx.x * BLOCK + threadIdx.x; i < M4; i += TPS) {
        f32x4 a = p[i], b = t[i];
        #pragma unroll
        for (int q = 0; q < 4; ++q) {
            float d = a[q] - b[q], ad = fabsf(d);
            s += (ad <= c) ? ad : (d * d + c2) * inv2c;
        }
    }
    s = wave_reduce_sum(s);
    __shared__ float ssum[BLOCK / 64];
    if ((threadIdx.x & 63) == 0) ssum[threadIdx.x >> 6] = s;
    __syncthreads();
    if (threadIdx.x == 0) {
        float bs = ssum[0];
        for (int w = 1; w < BLOCK / 64; ++w) bs += ssum[w];
        atomicAdd(out, bs * SCALE);
    }
}

extern "C" void kernel_launch(void* const* d_in, const int* in_sizes, int n_in,
                              void* d_out, int out_size, void* d_ws, size_t ws_size,
                              hipStream_t stream) {
    const float* pred = (const float*)d_in[0];
    const float* targ = (const float*)d_in[1];
    float* out = (float*)d_out;

    unsigned int* maxbits = (unsigned int*)d_ws;              // [64]
    unsigned int* done    = (unsigned int*)d_ws + N_SAMPLES;  // [64]

    // ws/out poisoned 0xAA, not re-poisoned between replays — zero every call.
    hipMemsetAsync(d_ws, 0, 2 * N_SAMPLES * sizeof(unsigned int), stream);
    hipMemsetAsync(d_out, 0, sizeof(float), stream);

    // Residency gate for the per-sample spin-sync (deterministic host query,
    // stream-independent, capture-safe).
    int nb = 0;
    hipError_t qe = hipOccupancyMaxActiveBlocksPerMultiprocessor(
        &nb, (const void*)berhu_fused, BLOCK, 0);
    const bool coop_ok = (qe == hipSuccess) && (nb * NUM_CU >= NBLOCKS);

    dim3 grid(BPS, N_SAMPLES);
    if (coop_ok) {
        berhu_fused<<<grid, BLOCK, 0, stream>>>(pred, targ, maxbits, done, out);
    } else {
        fb_max<<<grid, BLOCK, 0, stream>>>(pred, targ, maxbits);
        fb_sum<<<grid, BLOCK, 0, stream>>>(pred, targ, maxbits, out);
    }
}